// Round 9
// baseline (137.629 us; speedup 1.0000x reference)
//
#include <hip/hip_runtime.h>
#include <math.h>

// out[b,i,j,f] = min_{di,dj,c} ( x[b,i+di,j+dj,c] - W[di,dj,c,f] )
// x: (16,128,128,16) f32, W: (3,3,16,32) f32, out: (16,126,126,32) f32
//
// R9: one output scalar per thread (all 16 c in-thread, packed fp16).
// Kills the per-iteration __shfl_xor (ds_swizzle + lgkmcnt(0) serialized
// every steady iter in R3-R8 -> ~70% issue-idle). Block = 32f x 8cols;
// W slice = 72 h2 regs; per row: 6 ds_read_b128 -> 144 packed math insts
// (math:read 24:1), tail = 1 v_min_f16 + cvt + fully-coalesced store
// (no cross-lane, no waitcnt in store path). Tile (23 rows x 10 cols x
// 16c fp16 = 7.4KB) staged fp32->fp16 cooperatively. No launch_bounds
// VGPR cap (R4: forced cap -> scratch spill catastrophe).

#define TI 21           // output rows per block; 126 = 21*6
#define TROWS (TI + 2)  // input rows per tile (23)
#define TCOLS 10        // 8 output cols + 2 halo
#define CROW (TCOLS * 16)  // halves per tile row (160)

typedef _Float16 h2 __attribute__((ext_vector_type(2)));

__device__ __forceinline__ h2 hmin2(h2 a, h2 b) {
    return __builtin_elementwise_min(a, b);  // v_pk_min_f16
}

__device__ __forceinline__ h2 pkrtz(float a, float b) {
    auto r = __builtin_amdgcn_cvt_pkrtz(a, b);  // v_cvt_pkrtz_f16_f32
    return *reinterpret_cast<h2*>(&r);
}

__global__ __launch_bounds__(256) void erosion_kernel(
    const float* __restrict__ x, const float* __restrict__ Wt,
    float* __restrict__ out)
{
    __shared__ _Float16 lds[TROWS * CROW];  // 7360 B

    const int tid = threadIdx.x;
    const int f  = tid & 31;
    const int jt = tid >> 5;         // 0..7 column in block
    const int b  = blockIdx.z;
    const int i0 = blockIdx.y * TI;
    const int jb = blockIdx.x * 8;
    const int j  = jb + jt;          // 0..127
    const bool writer = (j < 126);

    // ---- cooperative tile stage: fp32 -> fp16 LDS [row][col][c] ----
    // chunk t (t < 23*40): r=t/40, k=t%40 -> col=jb+k/4, c-quad=k&3.
    // 16B fp32 global read -> 8B fp16 LDS write; per row 640B contiguous.
    {
        const float* xg = x + (size_t)b * (128 * 128 * 16);
        for (int t = tid; t < TROWS * 40; t += 256) {
            int r   = t / 40;
            int k   = t % 40;
            int cc  = k >> 2;                 // 0..9 tile column
            int q4  = k & 3;                  // c-quad
            int col = min(jb + cc, 127);      // clamp: feeds never-stored outputs only
            const float* src = xg + ((size_t)(i0 + r) * 128 + col) * 16 + q4 * 4;
            float4 v = *reinterpret_cast<const float4*>(src);
            h2 o[2] = { pkrtz(v.x, v.y), pkrtz(v.z, v.w) };
            *reinterpret_cast<double*>(&lds[r * CROW + cc * 16 + q4 * 4]) =
                *reinterpret_cast<double*>(o);   // ds_write_b64, 8B-aligned
        }
    }

    // ---- W slice in regs: wh[di][dj][q] = {W[di,dj,2q,f], W[di,dj,2q+1,f]} ----
    h2 wh[3][3][8];
#pragma unroll
    for (int di = 0; di < 3; ++di)
#pragma unroll
        for (int dj = 0; dj < 3; ++dj)
#pragma unroll
            for (int q = 0; q < 8; ++q) {
                int p = di * 3 + dj;
                float a = Wt[(p * 16 + 2 * q) * 32 + f];
                float c = Wt[(p * 16 + 2 * q + 1) * 32 + f];
                wh[di][dj][q] = pkrtz(a, c);
            }

    __syncthreads();

    const _Float16* lb = &lds[jt * 16];  // tile row 0, this thread's column
    float* op = out + (((size_t)b * 126 + i0) * 126 + j) * 32 + f;

    const _Float16 HINF = (_Float16)__builtin_huge_valf();
    h2 accB = {HINF, HINF};  // partial min for output row r-1
    h2 accC = {HINF, HINF};  // partial min for output row r-2

    auto body = [&](int r, bool do_store) {
        // this row's 3 cols x 16 c: 6 ds_read_b128, 2-address broadcast
        h2 hx[3][8];
#pragma unroll
        for (int dj = 0; dj < 3; ++dj) {
            float4 lo = *reinterpret_cast<const float4*>(lb + r * CROW + dj * 16);
            float4 hi = *reinterpret_cast<const float4*>(lb + r * CROW + dj * 16 + 8);
            const h2* pl = reinterpret_cast<const h2*>(&lo);
            const h2* ph = reinterpret_cast<const h2*>(&hi);
#pragma unroll
            for (int q = 0; q < 4; ++q) { hx[dj][q] = pl[q]; hx[dj][4 + q] = ph[q]; }
        }

        // three weight rows' contributions from this input row
        h2 n[3];
#pragma unroll
        for (int di = 0; di < 3; ++di) {
            h2 t[24];
#pragma unroll
            for (int dj = 0; dj < 3; ++dj)
#pragma unroll
                for (int q = 0; q < 8; ++q)
                    t[dj * 8 + q] = hx[dj][q] - wh[di][dj][q];  // v_pk_add_f16 neg
#pragma unroll
            for (int k = 0; k < 12; ++k) t[k] = hmin2(t[k], t[k + 12]);
#pragma unroll
            for (int k = 0; k < 6; ++k)  t[k] = hmin2(t[k], t[k + 6]);
#pragma unroll
            for (int k = 0; k < 3; ++k)  t[k] = hmin2(t[k], t[k + 3]);
            n[di] = hmin2(hmin2(t[0], t[1]), t[2]);
        }

        h2 fin2 = hmin2(accC, n[2]);  // output row r-2 complete
        accC = hmin2(accB, n[1]);
        accB = n[0];

        if (do_store) {
            _Float16 a = fin2[0], c = fin2[1];
            _Float16 vm = a < c ? a : c;      // v_min_f16 (hi/lo halves)
            if (writer)
                op[(size_t)(r - 2) * (126 * 32)] = (float)vm;
        }
    };

    body(0, false);
    body(1, false);
#pragma unroll 3
    for (int r = 2; r < TROWS; ++r)   // 21 steady iters
        body(r, true);
}

extern "C" void kernel_launch(void* const* d_in, const int* in_sizes, int n_in,
                              void* d_out, int out_size, void* d_ws, size_t ws_size,
                              hipStream_t stream) {
    const float* x  = (const float*)d_in[0];  // 16*128*128*16
    const float* Wt = (const float*)d_in[1];  // 3*3*16*32
    float* out = (float*)d_out;               // 16*126*126*32

    dim3 grid(16, 6, 16);   // 16 j-blocks x 6 row-blocks x 16 batches = 1536
    dim3 block(256);
    erosion_kernel<<<grid, block, 0, stream>>>(x, Wt, out);
}

// Round 10
// 109.802 us; speedup vs baseline: 1.2534x; 1.2534x over previous
//
#include <hip/hip_runtime.h>
#include <math.h>

// out[b,i,j,f] = min_{di,dj,c} ( x[b,i+di,j+dj,c] - W[di,dj,c,f] )
// x: (16,128,128,16) f32, W: (3,3,16,32) f32, out: (16,126,126,32) f32
//
// R10: R7 mapping (32f x 2ch x 4col, TI=21, 3072 blocks, fused fp32->fp16
// LDS tile) but the per-iteration __shfl_xor merge (ds_swizzle + lgkmcnt
// wait in EVERY steady iter -> in-order issue stalls ~120cy/iter) is
// replaced by: in-loop ds_write_b16 of the per-thread row result (no
// consumer -> no wait), then ONE barrier + a batched all-thread merge
// epilogue (full lane efficiency, coalesced stores). Steady body is pure:
// 3 prefetched ds_read_b128 + 71 packed-fp16 math + 1 v_min_f16 + 1 write.

#define TI 21           // output rows per block; 126 = 21*6
#define TROWS (TI + 2)  // input rows per tile (23)
#define LROW 64         // tile row stride in halves (48 used + pad)
#define VMS 26          // vm buffer stride in halves (13 dwords, coprime 32)

typedef _Float16 h2 __attribute__((ext_vector_type(2)));

__device__ __forceinline__ h2 hmin2(h2 a, h2 b) {
    return __builtin_elementwise_min(a, b);  // v_pk_min_f16
}

__device__ __forceinline__ h2 pkrtz(float a, float b) {
    auto r = __builtin_amdgcn_cvt_pkrtz(a, b);  // v_cvt_pkrtz_f16_f32
    return *reinterpret_cast<h2*>(&r);
}

// min over 12 half2 of (hx[k] - w[k]) for one weight row di
__device__ __forceinline__ h2 rowmin(const h2* hx, const h2 w[3][4]) {
    h2 t[12];
#pragma unroll
    for (int dj = 0; dj < 3; ++dj)
#pragma unroll
        for (int q = 0; q < 4; ++q)
            t[dj * 4 + q] = hx[dj * 4 + q] - w[dj][q];  // v_pk_add_f16 neg
#pragma unroll
    for (int k = 0; k < 6; ++k) t[k] = hmin2(t[k], t[k + 6]);
    t[0] = hmin2(t[0], t[3]);
    t[1] = hmin2(t[1], t[4]);
    t[2] = hmin2(t[2], t[5]);
    return hmin2(hmin2(t[0], t[1]), t[2]);
}

__global__ __launch_bounds__(256) void erosion_kernel(
    const float* __restrict__ x, const float* __restrict__ Wt,
    float* __restrict__ out)
{
    // tile: [ch:2][row:23][LROW=64 halves] = 5888 B
    __shared__ _Float16 tile[2 * TROWS * LROW];
    // per-thread row results: [tid:256][VMS=26 halves] = 13312 B
    __shared__ _Float16 vmbuf[256 * VMS];

    const int tid = threadIdx.x;
    const int f  = tid & 31;
    const int ch = (tid >> 5) & 1;   // channel half: 0 -> c 0..7, 1 -> c 8..15
    const int jt = tid >> 6;         // column in block (wave-uniform)
    const int b  = blockIdx.z;
    const int i0 = blockIdx.y * TI;
    const int jb = blockIdx.x * 4;

    // ---- fused stage: fp32 tile -> fp16 LDS (23 rows x 6 cols x 2 ch) ----
    // chunk t (t < 276): r = t/12, k = t%12 -> col = jb + k/2, ch2 = k&1.
    {
        const float* xg = x + (size_t)b * (128 * 128 * 16);
#pragma unroll
        for (int pass = 0; pass < 2; ++pass) {
            int t = tid + pass * 256;
            if (t < TROWS * 12) {
                int r   = t / 12;
                int k   = t % 12;
                int cc  = k >> 1;          // 0..5 tile column
                int ch2 = k & 1;
                int col = min(jb + cc, 127);  // clamp: feeds never-stored outputs only
                const float* src = xg + ((size_t)(i0 + r) * 128 + col) * 16 + ch2 * 8;
                float4 lo = *reinterpret_cast<const float4*>(src);
                float4 hi = *reinterpret_cast<const float4*>(src + 4);
                h2 o[4] = { pkrtz(lo.x, lo.y), pkrtz(lo.z, lo.w),
                            pkrtz(hi.x, hi.y), pkrtz(hi.z, hi.w) };
                *reinterpret_cast<float4*>(
                    &tile[ch2 * (TROWS * LROW) + r * LROW + cc * 8]) =
                    *reinterpret_cast<float4*>(o);
            }
        }
    }

    // wh[di][dj][q] = { W[di,dj, ch*8+2q, f], W[di,dj, ch*8+2q+1, f] } as fp16
    h2 wh[3][3][4];
#pragma unroll
    for (int di = 0; di < 3; ++di)
#pragma unroll
        for (int dj = 0; dj < 3; ++dj)
#pragma unroll
            for (int q = 0; q < 4; ++q) {
                int p = di * 3 + dj;
                float a = Wt[(p * 16 + ch * 8 + 2 * q) * 32 + f];
                float c = Wt[(p * 16 + ch * 8 + 2 * q + 1) * 32 + f];
                wh[di][dj][q] = pkrtz(a, c);
            }

    __syncthreads();

    const _Float16* lb = &tile[ch * (TROWS * LROW) + jt * 8];  // row 0, col jt
    _Float16* vmp = &vmbuf[tid * VMS];

    const _Float16 HINF = (_Float16)__builtin_huge_valf();
    h2 accB = {HINF, HINF};  // partial min for output row r-1
    h2 accC = {HINF, HINF};  // partial min for output row r-2

    // pipeline regs: current row's 3 col-spans (16B each, contiguous in LDS)
    float4 pre[3];
#pragma unroll
    for (int dj = 0; dj < 3; ++dj)
        pre[dj] = *reinterpret_cast<const float4*>(lb + dj * 8);

    auto body = [&](int r, bool do_prefetch, bool do_vm) {
        h2 hx[12];
#pragma unroll
        for (int dj = 0; dj < 3; ++dj) {
            const h2* p = reinterpret_cast<const h2*>(&pre[dj]);
            hx[dj * 4 + 0] = p[0];
            hx[dj * 4 + 1] = p[1];
            hx[dj * 4 + 2] = p[2];
            hx[dj * 4 + 3] = p[3];
        }
        if (do_prefetch) {
            const _Float16* ln = lb + (r + 1) * LROW;
#pragma unroll
            for (int dj = 0; dj < 3; ++dj)
                pre[dj] = *reinterpret_cast<const float4*>(ln + dj * 8);
        }

        h2 n0 = rowmin(hx, wh[0]);
        h2 n1 = rowmin(hx, wh[1]);
        h2 n2 = rowmin(hx, wh[2]);

        h2 fin2 = hmin2(accC, n2);  // output row r-2 complete
        accC = hmin2(accB, n1);
        accB = n0;

        if (do_vm) {
            _Float16 a = fin2[0], c = fin2[1];
            _Float16 vm = a < c ? a : c;   // v_min_f16
            vmp[r - 2] = vm;               // ds_write_b16: no consumer, no wait
        }
    };

    body(0, true, false);
    body(1, true, false);
#pragma unroll 3
    for (int r = 2; r < TROWS - 1; ++r)
        body(r, true, true);
    body(TROWS - 1, false, true);

    __syncthreads();

    // ---- batched merge epilogue: all 256 threads, coalesced stores ----
    // output (row, m) with m = col*32 + ff; partials live at threads
    // col*64 + ff (ch0) and col*64 + 32 + ff (ch1), slot row.
    {
        float* outb = out + (size_t)b * (126 * 126 * 32);
        for (int t = tid; t < TI * 128; t += 256) {
            int row = t >> 7;
            int m   = t & 127;
            int col = m >> 5;
            int ff  = m & 31;
            int jj  = jb + col;
            _Float16 a = vmbuf[(col * 64 + ff) * VMS + row];
            _Float16 c = vmbuf[(col * 64 + 32 + ff) * VMS + row];
            _Float16 vm = a < c ? a : c;
            if (jj < 126)
                outb[((size_t)(i0 + row) * 126 + jj) * 32 + ff] = (float)vm;
        }
    }
}

extern "C" void kernel_launch(void* const* d_in, const int* in_sizes, int n_in,
                              void* d_out, int out_size, void* d_ws, size_t ws_size,
                              hipStream_t stream) {
    const float* x  = (const float*)d_in[0];  // 16*128*128*16
    const float* Wt = (const float*)d_in[1];  // 3*3*16*32
    float* out = (float*)d_out;               // 16*126*126*32

    dim3 grid(32, 6, 16);   // 3072 blocks
    dim3 block(256);
    erosion_kernel<<<grid, block, 0, stream>>>(x, Wt, out);
}

// Round 12
// 109.561 us; speedup vs baseline: 1.2562x; 1.0022x over previous
//
#include <hip/hip_runtime.h>
#include <math.h>

// out[b,i,j,f] = min_{di,dj,c} ( x[b,i+di,j+dj,c] - W[di,dj,c,f] )
// x: (16,128,128,16) f32, W: (3,3,16,32) f32, out: (16,126,126,32) f32
//
// R12: consolidation on R10 (best passing config, no d_ws -- R11's two-pass
// ws structure failed post-timing re-validation and is abandoned).
// Single fused kernel: fp32 tile -> pkrtz -> fp16 LDS, packed-fp16 rolling
// window (irreducible ~71 packed insts/iter/thread), per-thread row results
// to vmbuf (fire-and-forget b16), then a PACKED merge epilogue: 4 outputs
// per task via 2 ds_read_b64 + 2 v_pk_min_f16 + float4 store. Steady loop
// has no global stores, no cross-lane ops, ds addressing folded to
// immediate offsets.

#define TI 21           // output rows per block; 126 = 21*6
#define TROWS (TI + 2)  // input rows per tile (23)
#define LROW 64         // tile row stride in halves (48 used + pad)

typedef _Float16 h2 __attribute__((ext_vector_type(2)));

__device__ __forceinline__ h2 hmin2(h2 a, h2 b) {
    return __builtin_elementwise_min(a, b);  // v_pk_min_f16
}

__device__ __forceinline__ h2 pkrtz(float a, float b) {
    auto r = __builtin_amdgcn_cvt_pkrtz(a, b);  // v_cvt_pkrtz_f16_f32
    return *reinterpret_cast<h2*>(&r);
}

// min over 12 half2 of (pr[k] - w[k]) for one weight row di; consumes the
// prefetch registers directly (SSA, no copies).
__device__ __forceinline__ h2 rowmin3(const float4* pr, const h2 w[3][4]) {
    h2 t[12];
#pragma unroll
    for (int dj = 0; dj < 3; ++dj) {
        const h2* p = reinterpret_cast<const h2*>(&pr[dj]);
#pragma unroll
        for (int q = 0; q < 4; ++q)
            t[dj * 4 + q] = p[q] - w[dj][q];  // v_pk_add_f16 neg
    }
#pragma unroll
    for (int k = 0; k < 6; ++k) t[k] = hmin2(t[k], t[k + 6]);
    t[0] = hmin2(t[0], t[3]);
    t[1] = hmin2(t[1], t[4]);
    t[2] = hmin2(t[2], t[5]);
    return hmin2(hmin2(t[0], t[1]), t[2]);
}

__global__ __launch_bounds__(256) void erosion_kernel(
    const float* __restrict__ x, const float* __restrict__ Wt,
    float* __restrict__ out)
{
    __shared__ _Float16 tile[2 * TROWS * LROW];  // 5888 B
    __shared__ _Float16 vmbuf[TI * 256];         // 10752 B

    const int tid = threadIdx.x;
    const int f  = tid & 31;
    const int ch = (tid >> 5) & 1;   // channel half: 0 -> c 0..7, 1 -> c 8..15
    const int jt = tid >> 6;         // column in block (wave-uniform)
    const int b  = blockIdx.z;
    const int i0 = blockIdx.y * TI;
    const int jb = blockIdx.x * 4;

    // ---- fused stage: fp32 tile -> fp16 LDS (23 rows x 6 cols x 2 ch) ----
    // chunk t (t < 276): r = t/12, k = t%12 -> col = jb + k/2, ch2 = k&1.
    {
        const float* xg = x + (size_t)b * (128 * 128 * 16);
        auto stage = [&](int t) {
            int r   = t / 12;
            int k   = t % 12;
            int cc  = k >> 1;          // 0..5 tile column
            int ch2 = k & 1;
            int col = min(jb + cc, 127);  // clamp: feeds never-stored outputs only
            const float* src = xg + ((size_t)(i0 + r) * 128 + col) * 16 + ch2 * 8;
            float4 lo = *reinterpret_cast<const float4*>(src);
            float4 hi = *reinterpret_cast<const float4*>(src + 4);
            h2 o[4] = { pkrtz(lo.x, lo.y), pkrtz(lo.z, lo.w),
                        pkrtz(hi.x, hi.y), pkrtz(hi.z, hi.w) };
            *reinterpret_cast<float4*>(
                &tile[ch2 * (TROWS * LROW) + r * LROW + cc * 8]) =
                *reinterpret_cast<float4*>(o);
        };
        stage(tid);
        if (tid < TROWS * 12 - 256) stage(tid + 256);  // 20 extra chunks
    }

    // wh[di][dj][q] = { W[di,dj, ch*8+2q, f], W[di,dj, ch*8+2q+1, f] } as fp16
    h2 wh[3][3][4];
#pragma unroll
    for (int di = 0; di < 3; ++di)
#pragma unroll
        for (int dj = 0; dj < 3; ++dj)
#pragma unroll
            for (int q = 0; q < 4; ++q) {
                int p = di * 3 + dj;
                float a = Wt[(p * 16 + ch * 8 + 2 * q) * 32 + f];
                float c = Wt[(p * 16 + ch * 8 + 2 * q + 1) * 32 + f];
                wh[di][dj][q] = pkrtz(a, c);
            }

    __syncthreads();

    const _Float16* lb = &tile[ch * (TROWS * LROW) + jt * 8];  // row 0, col jt

    const _Float16 HINF = (_Float16)__builtin_huge_valf();
    h2 accB = {HINF, HINF};  // partial min for output row r-1
    h2 accC = {HINF, HINF};  // partial min for output row r-2

    // depth-1 prefetch regs: current row's 3 col-spans (16B each)
    float4 pre[3];
#pragma unroll
    for (int dj = 0; dj < 3; ++dj)
        pre[dj] = *reinterpret_cast<const float4*>(lb + dj * 8);

    auto body = [&](int r, bool do_prefetch, bool do_vm) {
        h2 n0 = rowmin3(pre, wh[0]);
        h2 n1 = rowmin3(pre, wh[1]);
        h2 n2 = rowmin3(pre, wh[2]);

        if (do_prefetch) {
            const _Float16* ln = lb + (r + 1) * LROW;
#pragma unroll
            for (int dj = 0; dj < 3; ++dj)
                pre[dj] = *reinterpret_cast<const float4*>(ln + dj * 8);
        }

        h2 fin2 = hmin2(accC, n2);  // output row r-2 complete
        accC = hmin2(accB, n1);
        accB = n0;

        if (do_vm) {
            _Float16 a = fin2[0], c = fin2[1];
            _Float16 vm = a < c ? a : c;          // v_min_f16
            vmbuf[(r - 2) * 256 + tid] = vm;      // b16 write, no consumer wait
        }
    };

    body(0, true, false);
    body(1, true, false);
#pragma unroll 2
    for (int r = 2; r < TROWS - 1; ++r)   // r = 2..21
        body(r, true, true);
    body(TROWS - 1, false, true);         // r = 22, no prefetch

    __syncthreads();

    // ---- packed merge epilogue: 4 outputs per task ----
    // task t (t < TI*32): row = t/32, k = t%32, col = k>>3, q = k&7.
    // partials: ch0 at vmbuf[row*256 + col*64 + 4q .. +3],
    //           ch1 at vmbuf[row*256 + col*64 + 32 + 4q .. +3].
    {
        float* outb = out + (size_t)b * (126 * 126 * 32);
        auto merge = [&](int t) {
            int row = t >> 5;
            int k   = t & 31;
            int col = k >> 3;
            int q   = k & 7;
            int jj  = jb + col;
            const _Float16* base = &vmbuf[row * 256 + col * 64 + q * 4];
            h2 a[2], c[2];
            *reinterpret_cast<double*>(a) = *reinterpret_cast<const double*>(base);
            *reinterpret_cast<double*>(c) = *reinterpret_cast<const double*>(base + 32);
            h2 m0 = hmin2(a[0], c[0]);
            h2 m1 = hmin2(a[1], c[1]);
            float4 o = { (float)m0[0], (float)m0[1], (float)m1[0], (float)m1[1] };
            if (jj < 126)
                *reinterpret_cast<float4*>(
                    &outb[((size_t)(i0 + row) * 126 + jj) * 32 + q * 4]) = o;
        };
        merge(tid);
        merge(tid + 256);
        if (tid < TI * 32 - 512) merge(tid + 512);  // 160 extra tasks
    }
}

extern "C" void kernel_launch(void* const* d_in, const int* in_sizes, int n_in,
                              void* d_out, int out_size, void* d_ws, size_t ws_size,
                              hipStream_t stream) {
    const float* x  = (const float*)d_in[0];  // 16*128*128*16
    const float* Wt = (const float*)d_in[1];  // 3*3*16*32
    float* out = (float*)d_out;               // 16*126*126*32

    dim3 grid(32, 6, 16);   // 3072 blocks
    dim3 block(256);
    erosion_kernel<<<grid, block, 0, stream>>>(x, Wt, out);
}

// Round 13
// 107.958 us; speedup vs baseline: 1.2748x; 1.0148x over previous
//
#include <hip/hip_runtime.h>
#include <math.h>

// out[b,i,j,f] = min_{di,dj,c} ( x[b,i+di,j+dj,c] - W[di,dj,c,f] )
// x: (16,128,128,16) f32, W: (3,3,16,32) f32, out: (16,126,126,32) f32
//
// R13 = R12 skeleton (fused single kernel, fp16 LDS tile, packed-fp16
// rolling window, vmbuf + packed merge epilogue) with two inst-count cuts:
//  1. W-prologue via coalesced LDS bounce: 4608 W floats staged packed-h2
//     by the whole block (9 coalesced rounds/thread), then 36 conflict-free
//     ds_read_b32 per thread -- replaces 72 scattered global loads + 36 cvt
//     per thread (~150 insts -> ~45+36).  wlds overlays vmbuf (barrier
//     separates W-reads from vm-writes).
//  2. Steady 23-row loop FULLY unrolled: compile-time r -> immediate ds
//     offsets, zero loop overhead, compiler free to hoist ds_reads across
//     rows (VGPR headroom 48 -> 64).

#define TI 21           // output rows per block; 126 = 21*6
#define TROWS (TI + 2)  // input rows per tile (23)
#define LROW 64         // tile row stride in halves (48 used + pad)

typedef _Float16 h2 __attribute__((ext_vector_type(2)));

__device__ __forceinline__ h2 hmin2(h2 a, h2 b) {
    return __builtin_elementwise_min(a, b);  // v_pk_min_f16
}

__device__ __forceinline__ h2 pkrtz(float a, float b) {
    auto r = __builtin_amdgcn_cvt_pkrtz(a, b);  // v_cvt_pkrtz_f16_f32
    return *reinterpret_cast<h2*>(&r);
}

// min over 12 half2 of (pr[k] - w[k]) for one weight row di; consumes the
// prefetch registers directly (SSA, no copies).
__device__ __forceinline__ h2 rowmin3(const float4* pr, const h2 w[3][4]) {
    h2 t[12];
#pragma unroll
    for (int dj = 0; dj < 3; ++dj) {
        const h2* p = reinterpret_cast<const h2*>(&pr[dj]);
#pragma unroll
        for (int q = 0; q < 4; ++q)
            t[dj * 4 + q] = p[q] - w[dj][q];  // v_pk_add_f16 neg
    }
#pragma unroll
    for (int k = 0; k < 6; ++k) t[k] = hmin2(t[k], t[k + 6]);
    t[0] = hmin2(t[0], t[3]);
    t[1] = hmin2(t[1], t[4]);
    t[2] = hmin2(t[2], t[5]);
    return hmin2(hmin2(t[0], t[1]), t[2]);
}

__global__ __launch_bounds__(256) void erosion_kernel(
    const float* __restrict__ x, const float* __restrict__ Wt,
    float* __restrict__ out)
{
    __shared__ _Float16 tile[2 * TROWS * LROW];  // 5888 B
    // union buffer: first holds packed W (4608 halves = 9216 B), then
    // reused as vmbuf (TI*256 = 5376 halves = 10752 B). 10752 B allocated.
    __shared__ _Float16 wvm[TI * 256];

    const int tid = threadIdx.x;
    const int f  = tid & 31;
    const int ch = (tid >> 5) & 1;   // channel half: 0 -> c 0..7, 1 -> c 8..15
    const int jt = tid >> 6;         // column in block (wave-uniform)
    const int b  = blockIdx.z;
    const int i0 = blockIdx.y * TI;
    const int jb = blockIdx.x * 4;

    // ---- stage x tile: fp32 -> fp16 LDS (23 rows x 6 cols x 2 ch) ----
    // chunk t (t < 276): r = t/12, k = t%12 -> col = jb + k/2, ch2 = k&1.
    {
        const float* xg = x + (size_t)b * (128 * 128 * 16);
        auto stage = [&](int t) {
            int r   = t / 12;
            int k   = t % 12;
            int cc  = k >> 1;          // 0..5 tile column
            int ch2 = k & 1;
            int col = min(jb + cc, 127);  // clamp: feeds never-stored outputs only
            const float* src = xg + ((size_t)(i0 + r) * 128 + col) * 16 + ch2 * 8;
            float4 lo = *reinterpret_cast<const float4*>(src);
            float4 hi = *reinterpret_cast<const float4*>(src + 4);
            h2 o[4] = { pkrtz(lo.x, lo.y), pkrtz(lo.z, lo.w),
                        pkrtz(hi.x, hi.y), pkrtz(hi.z, hi.w) };
            *reinterpret_cast<float4*>(
                &tile[ch2 * (TROWS * LROW) + r * LROW + cc * 8]) =
                *reinterpret_cast<float4*>(o);
        };
        stage(tid);
        if (tid < TROWS * 12 - 256) stage(tid + 256);  // 20 extra chunks
    }

    // ---- stage W packed-h2 into wvm: wl[g*32 + f] = {W[.,2c,f],W[.,2c+1,f]}
    // g = p*8 + cpair (p = di*3+dj, cpair = c/2); W flat idx = g*64 + f.
    {
        h2* wl = reinterpret_cast<h2*>(wvm);
#pragma unroll
        for (int rr = 0; rr < 9; ++rr) {          // 2304 tasks = 9 * 256
            int t  = rr * 256 + tid;
            int g  = t >> 5;
            int ff = t & 31;
            float a  = Wt[g * 64 + ff];
            float c2 = Wt[g * 64 + 32 + ff];
            wl[g * 32 + ff] = pkrtz(a, c2);
        }
    }

    __syncthreads();

    // ---- read this thread's W frags: 36 conflict-free ds_read_b32 ----
    h2 wh[3][3][4];
    {
        const h2* wl = reinterpret_cast<const h2*>(wvm);
#pragma unroll
        for (int p = 0; p < 9; ++p)
#pragma unroll
            for (int q = 0; q < 4; ++q)
                wh[p / 3][p % 3][q] = wl[(p * 8 + ch * 4 + q) * 32 + f];
    }

    const _Float16* lb = &tile[ch * (TROWS * LROW) + jt * 8];  // row 0, col jt

    // prime depth-1 prefetch regs (tile is ready; wvm reads still pending
    // but wh uses force lgkmcnt before first rowmin anyway)
    float4 pre[3];
#pragma unroll
    for (int dj = 0; dj < 3; ++dj)
        pre[dj] = *reinterpret_cast<const float4*>(lb + dj * 8);

    __syncthreads();   // all W reads done before any vm write overlays wvm

    const _Float16 HINF = (_Float16)__builtin_huge_valf();
    h2 accB = {HINF, HINF};  // partial min for output row r-1
    h2 accC = {HINF, HINF};  // partial min for output row r-2

    auto body = [&](int r, bool do_prefetch, bool do_vm) {
        h2 n0 = rowmin3(pre, wh[0]);
        h2 n1 = rowmin3(pre, wh[1]);
        h2 n2 = rowmin3(pre, wh[2]);

        if (do_prefetch) {
            const _Float16* ln = lb + (r + 1) * LROW;
#pragma unroll
            for (int dj = 0; dj < 3; ++dj)
                pre[dj] = *reinterpret_cast<const float4*>(ln + dj * 8);
        }

        h2 fin2 = hmin2(accC, n2);  // output row r-2 complete
        accC = hmin2(accB, n1);
        accB = n0;

        if (do_vm) {
            _Float16 a = fin2[0], c = fin2[1];
            _Float16 vm = a < c ? a : c;          // v_min_f16
            wvm[(r - 2) * 256 + tid] = vm;        // b16 write, no consumer wait
        }
    };

    body(0, true, false);
    body(1, true, false);
#pragma unroll
    for (int r = 2; r < TROWS - 1; ++r)   // FULL unroll: r = 2..21 literal
        body(r, true, true);
    body(TROWS - 1, false, true);         // r = 22, no prefetch

    __syncthreads();

    // ---- packed merge epilogue: 4 outputs per task ----
    // task t (t < TI*32): row = t>>5, k = t&31, col = k>>3, q = k&7.
    // partials: ch0 at wvm[row*256 + col*64 + 4q..+3], ch1 at +32.
    {
        float* outb = out + (size_t)b * (126 * 126 * 32);
        auto merge = [&](int t) {
            int row = t >> 5;
            int k   = t & 31;
            int col = k >> 3;
            int q   = k & 7;
            int jj  = jb + col;
            const _Float16* base = &wvm[row * 256 + col * 64 + q * 4];
            h2 a[2], c[2];
            *reinterpret_cast<double*>(a) = *reinterpret_cast<const double*>(base);
            *reinterpret_cast<double*>(c) = *reinterpret_cast<const double*>(base + 32);
            h2 m0 = hmin2(a[0], c[0]);
            h2 m1 = hmin2(a[1], c[1]);
            float4 o = { (float)m0[0], (float)m0[1], (float)m1[0], (float)m1[1] };
            if (jj < 126)
                *reinterpret_cast<float4*>(
                    &outb[((size_t)(i0 + row) * 126 + jj) * 32 + q * 4]) = o;
        };
        merge(tid);
        merge(tid + 256);
        if (tid < TI * 32 - 512) merge(tid + 512);  // 160 extra tasks
    }
}

extern "C" void kernel_launch(void* const* d_in, const int* in_sizes, int n_in,
                              void* d_out, int out_size, void* d_ws, size_t ws_size,
                              hipStream_t stream) {
    const float* x  = (const float*)d_in[0];  // 16*128*128*16
    const float* Wt = (const float*)d_in[1];  // 3*3*16*32
    float* out = (float*)d_out;               // 16*126*126*32

    dim3 grid(32, 6, 16);   // 3072 blocks
    dim3 block(256);
    erosion_kernel<<<grid, block, 0, stream>>>(x, Wt, out);
}